// Round 16
// baseline (224.881 us; speedup 1.0000x reference)
//
#include <hip/hip_runtime.h>
#include <hip/hip_bf16.h>

// ---------------------------------------------------------------------------
// DHN 2-layer hom-conv GNN.
// Round 16:
//  - csr_agg: 4 nodes/wave -> 32 gathers in flight per main iter (2x r12).
//  - sb_sort: 1024 threads (per-thread serial work halves, 32-wave occ).
// ---------------------------------------------------------------------------

#define CAPSB 9216        // per-(map,SB) p1 capacity: mean 8192 + ~11 sigma
#define CAPCOL 12800      // cols capacity: CAPSB + 512*7 padding
#define CHUNK 4096        // edges per pass-1 block
#define PTHREADS 512
#define EPT 8             // CHUNK / PTHREADS
#define SBSHIFT 9         // 512 nodes per super-bucket
#define POOLROWS 32       // rows per pool block

typedef __attribute__((ext_vector_type(8))) short bf16x8;
typedef __attribute__((ext_vector_type(4))) float f32x4;

__device__ inline unsigned short f2bf(float x) {           // RNE f32 -> bf16
    union { float f; unsigned u; } c; c.f = x;
    unsigned r = (c.u + 0x7FFFu + ((c.u >> 16) & 1u)) >> 16;
    return (unsigned short)r;
}
__device__ inline float bf2f(unsigned u16) {
    union { unsigned u; float f; } c; c.u = (u16 & 0xffffu) << 16; return c.f;
}
__device__ inline float lo16f(unsigned v) {   // low bf16 of packed dword
    union { unsigned u; float f; } c; c.u = v << 16; return c.f;
}
__device__ inline float hi16f(unsigned v) {   // high bf16 of packed dword
    union { unsigned u; float f; } c; c.u = v & 0xffff0000u; return c.f;
}

// ---- pack 6 weight matrices -> [K/8][64][8] bf16 frags.
// block 6: zero h dummy row N + cnt (6*NSB) + pooled (64*192).
__global__ void prepack_w(const float* __restrict__ W0, const float* __restrict__ W1,
                          const float* __restrict__ W2, const float* __restrict__ W3,
                          const float* __restrict__ W4, const float* __restrict__ W5,
                          unsigned short* __restrict__ wp,
                          unsigned short* __restrict__ h, int N,
                          int* __restrict__ cnt, int NSB,
                          float* __restrict__ pooled) {
    const int m = blockIdx.x;
    if (m == 6) {
        for (int i = threadIdx.x; i < 192; i += 256) h[(size_t)N * 192 + i] = 0;
        for (int i = threadIdx.x; i < 6 * NSB; i += 256) cnt[i] = 0;
        for (int i = threadIdx.x; i < 64 * 192; i += 256) pooled[i] = 0.f;
        return;
    }
    const float* W = (m == 0) ? W0 : (m == 1) ? W1 : (m == 2) ? W2
                   : (m == 3) ? W3 : (m == 4) ? W4 : W5;
    const int K = (m < 3) ? 128 : 192;
    unsigned short* o = wp + (size_t)m * 12288;
    for (int idx = threadIdx.x; idx < K * 64; idx += 256) {
        int k = idx >> 6, col = idx & 63;
        o[((k >> 3) * 64 + col) * 8 + (k & 7)] = f2bf(W[idx]);
    }
}

// ---- bf16 MFMA gemm: h[:, g*64..] = in[M,K]@Wg + bg, h bf16. ----
template <int INBF16>
__global__ void gemm_mfma(const void* __restrict__ in_, int M, int K,
                          const unsigned short* __restrict__ wpack,
                          const float* __restrict__ b0, const float* __restrict__ b1,
                          const float* __restrict__ b2, int mslot,
                          unsigned short* __restrict__ h) {
    __shared__ __align__(16) unsigned short Ws[12288];  // K*64 bf16, K<=192
    __shared__ __align__(16) unsigned short As[2048];   // 64 rows x 32 k, swizzled

    const int g = blockIdx.y;
    const float* bias = (g == 0) ? b0 : ((g == 1) ? b1 : b2);
    const unsigned short* wp = wpack + (size_t)(mslot + g) * 12288;

    const int t = threadIdx.x;
    for (int i = t; i < K * 32; i += 256)
        ((int*)Ws)[i] = ((const int*)wp)[i];

    const int m0   = blockIdx.x * 64;
    const int lane = t & 63;
    const int wrow = (t >> 6) * 16;

    const int arow = t >> 2;
    const int aseg = t & 3;
    const int aswz = arow * 32 + ((aseg ^ ((arow >> 1) & 3)) << 3);
    const int grow = m0 + arow;

    const float*          ainf = (const float*)in_ + (size_t)grow * K + aseg * 8;
    const unsigned short* ainb = (const unsigned short*)in_ + (size_t)grow * K + aseg * 8;

    const int lrow = wrow + (lane & 15);
    const int aoff = lrow * 32 + ((((lane >> 4)) ^ ((lrow >> 1) & 3)) << 3);
    const int kq   = lane >> 4;

    f32x4 acc[4] = {};

    const int nsteps = K >> 5;
    for (int s = 0; s < nsteps; ++s) {
        __syncthreads();
        bf16x8 av = {};
        if (grow < M) {
            if (INBF16) {
                av = *reinterpret_cast<const bf16x8*>(ainb + s * 32);
            } else {
                float4 v0 = *reinterpret_cast<const float4*>(ainf + s * 32);
                float4 v1 = *reinterpret_cast<const float4*>(ainf + s * 32 + 4);
                av[0] = (short)f2bf(v0.x); av[1] = (short)f2bf(v0.y);
                av[2] = (short)f2bf(v0.z); av[3] = (short)f2bf(v0.w);
                av[4] = (short)f2bf(v1.x); av[5] = (short)f2bf(v1.y);
                av[6] = (short)f2bf(v1.z); av[7] = (short)f2bf(v1.w);
            }
        }
        *reinterpret_cast<bf16x8*>(&As[aswz]) = av;
        __syncthreads();

        bf16x8 af = *reinterpret_cast<const bf16x8*>(&As[aoff]);
        const int kg = s * 4 + kq;
        #pragma unroll
        for (int n = 0; n < 4; ++n) {
            bf16x8 bfv = *reinterpret_cast<const bf16x8*>(
                &Ws[(size_t)(kg * 64 + n * 16 + (lane & 15)) * 8]);
            acc[n] = __builtin_amdgcn_mfma_f32_16x16x32_bf16(af, bfv, acc[n], 0, 0, 0);
        }
    }

    #pragma unroll
    for (int n = 0; n < 4; ++n) {
        int col = n * 16 + (lane & 15);
        float bv = bias[col];
        #pragma unroll
        for (int r = 0; r < 4; ++r) {
            int row = m0 + wrow + (lane >> 4) * 4 + r;
            if (row < M)
                h[(size_t)row * 192 + g * 64 + col] = f2bf(acc[n][r] + bv);
        }
    }
}

// ---- pass 1: coarse partition into 512-node super-buckets. ----
// Records LDS-staged ordered by SB, then copied out linearly (coalesced runs).
__global__ void part_coarse(const int* __restrict__ m0, const int* __restrict__ m1,
                            const int* __restrict__ m2, const int* __restrict__ m3,
                            const int* __restrict__ m4, const int* __restrict__ m5,
                            int E, int NSB, int* __restrict__ cnt,
                            unsigned* __restrict__ p1) {
    const int m = blockIdx.y;
    const int* mp = (m == 0) ? m0 : (m == 1) ? m1 : (m == 2) ? m2
                  : (m == 3) ? m3 : (m == 4) ? m4 : m5;
    __shared__ int hist[128];
    __shared__ int scanb[128];
    __shared__ int loff[128];
    __shared__ int delta[128];
    __shared__ unsigned stage[CHUNK];     // 16 KB
    const int c0 = blockIdx.x * CHUNK;
    const int t = threadIdx.x;

    int d[EPT]; unsigned srcs[EPT];
    #pragma unroll
    for (int k = 0; k < EPT; ++k) {
        int e = c0 + k * PTHREADS + t;
        bool v = e < E;
        d[k]    = v ? mp[e] : -1;
        srcs[k] = v ? (unsigned)mp[E + e] : 0u;
    }

    if (t < 128) hist[t] = 0;
    __syncthreads();
    #pragma unroll
    for (int k = 0; k < EPT; ++k)
        if (d[k] >= 0) atomicAdd(&hist[d[k] >> SBSHIFT], 1);
    __syncthreads();

    if (t < 128) scanb[t] = hist[t];
    __syncthreads();
    for (int off = 1; off < 128; off <<= 1) {
        int v = (t < 128 && t >= off) ? scanb[t - off] : 0;
        __syncthreads();
        if (t < 128) scanb[t] += v;
        __syncthreads();
    }
    if (t < NSB) {
        int c = hist[t];
        int lstart = scanb[t] - c;
        int gbase = (c > 0) ? atomicAdd(&cnt[m * NSB + t], c) : 0;
        loff[t]  = lstart;
        delta[t] = (m * NSB + t) * CAPSB + gbase - lstart;
    }
    __syncthreads();

    #pragma unroll
    for (int k = 0; k < EPT; ++k) {
        if (d[k] >= 0) {
            int sb = d[k] >> SBSHIFT;
            int pos = atomicAdd(&loff[sb], 1);
            stage[pos] = (srcs[k] << 16) | (unsigned)d[k];
        }
    }
    __syncthreads();

    const int total = scanb[127];
    for (int i = t; i < total; i += PTHREADS) {
        unsigned r = stage[i];
        int sb = (r & 0xffffu) >> SBSHIFT;
        int gidx = delta[sb] + i;
        if (gidx - (m * NSB + sb) * CAPSB < CAPSB)
            p1[gidx] = r;
    }
}

// ---- pass 2: per-(SB,map) counting sort -> padded CSR (u32 byte-offset cols).
// 1024 threads: per-thread serial work halved vs 512.
__global__ void sb_sort(int NSB, int N, const int* __restrict__ cnt,
                        const unsigned* __restrict__ p1,
                        unsigned* __restrict__ cols, int* __restrict__ rows) {
    const int sb = blockIdx.x;
    const int m  = blockIdx.y;
    __shared__ unsigned rec[CAPSB];
    __shared__ int bin[512];
    __shared__ int pend[512];
    __shared__ int scanbuf[512];
    const int t = threadIdx.x;    // 0..1023
    const size_t basep = (size_t)(m * NSB + sb) * CAPSB;
    const size_t basec = (size_t)(m * NSB + sb) * CAPCOL;
    const int c = min(cnt[m * NSB + sb], CAPSB);

    for (int i = t; i < c; i += 1024) rec[i] = p1[basep + i];
    if (t < 512) bin[t] = 0;
    __syncthreads();
    for (int i = t; i < c; i += 1024)
        atomicAdd(&bin[rec[i] & 511], 1);
    __syncthreads();

    int p0 = 0;
    if (t < 512) { int b0 = bin[t]; p0 = (b0 + 7) & ~7; scanbuf[t] = p0; }
    __syncthreads();
    for (int off = 1; off < 512; off <<= 1) {
        int v = (t < 512 && t >= off) ? scanbuf[t - off] : 0;
        __syncthreads();
        if (t < 512) scanbuf[t] += v;
        __syncthreads();
    }
    if (t < 512) {
        int excl = scanbuf[t] - p0;
        bin[t]  = excl;
        pend[t] = excl + p0;
        int n = (sb << SBSHIFT) + t;
        if (n < N) rows[(size_t)m * N + n] = (int)(basec + pend[t]);
    }
    __syncthreads();

    for (int i = t; i < c; i += 1024) {
        unsigned r = rec[i];
        int pos = atomicAdd(&bin[r & 511], 1);
        cols[basec + pos] = (r >> 16) * 384u;    // byte offset of h row
    }
    __syncthreads();

    if (t < 512) {
        const unsigned dummy = (unsigned)N * 384u;
        for (int k = bin[t]; k < pend[t]; ++k)
            cols[basec + k] = dummy;
    }
}

// ---- four nodes per wave; 32 dword gathers in flight in the main loop. ----
// half-wave takes 4 edges of each 8-edge group; cols are byte offsets.
__device__ inline void aggG(const char* __restrict__ hb,
                            const unsigned* __restrict__ cols,
                            int i, float& ax, float& ay) {  // one 8-edge group
    uint4 ca = *reinterpret_cast<const uint4*>(cols + i);   // i pre-offset by half
    unsigned v0 = *reinterpret_cast<const unsigned*>(hb + ca.x);
    unsigned v1 = *reinterpret_cast<const unsigned*>(hb + ca.y);
    unsigned v2 = *reinterpret_cast<const unsigned*>(hb + ca.z);
    unsigned v3 = *reinterpret_cast<const unsigned*>(hb + ca.w);
    ax += (lo16f(v0) + lo16f(v1)) + (lo16f(v2) + lo16f(v3));
    ay += (hi16f(v0) + hi16f(v1)) + (hi16f(v2) + hi16f(v3));
}

__global__ void csr_agg(const unsigned short* __restrict__ h, const int* __restrict__ rows,
                        const unsigned* __restrict__ cols, int N, int NSB, int mapBase,
                        unsigned short* __restrict__ f) {
    const int g = blockIdx.y;
    const int m = mapBase + g;
    const int lane = threadIdx.x & 63;
    const int half4 = (lane >> 5) << 2;  // 0: edges 0-3 of group, 4: edges 4-7
    const int fp = (lane & 31) * 2;      // feature pair base
    const int wid = (blockIdx.x * blockDim.x + threadIdx.x) >> 6;
    const int n0 = wid * 4;
    if (n0 >= N) return;

    int s[4], e[4];
    const size_t base0 = (size_t)(m * NSB + (n0 >> SBSHIFT)) * CAPCOL;
    s[0] = ((n0 & 511) == 0) ? (int)base0 : rows[(size_t)m * N + n0 - 1];
    e[0] = rows[(size_t)m * N + n0];
    #pragma unroll
    for (int j = 1; j < 4; ++j) {
        if (n0 + j < N) { s[j] = e[j - 1]; e[j] = rows[(size_t)m * N + n0 + j]; }
        else            { s[j] = 0;        e[j] = 0; }
    }
    const char* hb = (const char*)(h + g * 64 + fp);

    float ax[4] = {}, ay[4] = {};
    int idx[4], fin[4];
    #pragma unroll
    for (int j = 0; j < 4; ++j) { idx[j] = s[j] + half4; fin[j] = e[j] - 16 + half4; }

    // quad main loop: 16 edges of each of 4 nodes -> 32 dword gathers in flight
    while (idx[0] <= fin[0] && idx[1] <= fin[1] && idx[2] <= fin[2] && idx[3] <= fin[3]) {
        uint4 cv[8];
        #pragma unroll
        for (int j = 0; j < 4; ++j) {
            cv[2 * j]     = *reinterpret_cast<const uint4*>(cols + idx[j]);
            cv[2 * j + 1] = *reinterpret_cast<const uint4*>(cols + idx[j] + 8);
        }
        unsigned v[32];
        #pragma unroll
        for (int j = 0; j < 8; ++j) {
            v[4 * j + 0] = *reinterpret_cast<const unsigned*>(hb + cv[j].x);
            v[4 * j + 1] = *reinterpret_cast<const unsigned*>(hb + cv[j].y);
            v[4 * j + 2] = *reinterpret_cast<const unsigned*>(hb + cv[j].z);
            v[4 * j + 3] = *reinterpret_cast<const unsigned*>(hb + cv[j].w);
        }
        #pragma unroll
        for (int j = 0; j < 4; ++j) {
            ax[j] += ((lo16f(v[8*j+0]) + lo16f(v[8*j+1])) + (lo16f(v[8*j+2]) + lo16f(v[8*j+3])))
                   + ((lo16f(v[8*j+4]) + lo16f(v[8*j+5])) + (lo16f(v[8*j+6]) + lo16f(v[8*j+7])));
            ay[j] += ((hi16f(v[8*j+0]) + hi16f(v[8*j+1])) + (hi16f(v[8*j+2]) + hi16f(v[8*j+3])))
                   + ((hi16f(v[8*j+4]) + hi16f(v[8*j+5])) + (hi16f(v[8*j+6]) + hi16f(v[8*j+7])));
            idx[j] += 16;
        }
    }
    #pragma unroll
    for (int j = 0; j < 4; ++j) {
        while (idx[j] <= fin[j]) {
            aggG(hb, cols, idx[j], ax[j], ay[j]);
            aggG(hb, cols, idx[j] + 8, ax[j], ay[j]);
            idx[j] += 16;
        }
        if (idx[j] < e[j]) aggG(hb, cols, idx[j], ax[j], ay[j]);  // 8 remain (x8-pad)
    }

    #pragma unroll
    for (int j = 0; j < 4; ++j) { ax[j] += __shfl_xor(ax[j], 32); ay[j] += __shfl_xor(ay[j], 32); }
    if (half4 == 0) {
        #pragma unroll
        for (int j = 0; j < 4; ++j) {
            if (n0 + j < N) {
                unsigned pk = (unsigned)f2bf(fmaxf(ax[j], 0.f))
                            | ((unsigned)f2bf(fmaxf(ay[j], 0.f)) << 16);
                *reinterpret_cast<unsigned*>(f + (size_t)(n0 + j) * 192 + g * 64 + fp) = pk;
            }
        }
    }
}

// segment-pool bf16 f by sorted batch_idx; 32-row chunks for occupancy.
__global__ void pool_kernel(const unsigned short* __restrict__ f, const int* __restrict__ bidx,
                            int N, float* __restrict__ pooled) {
    const int c  = threadIdx.x;          // 0..191
    const int r0 = blockIdx.x * POOLROWS;
    const int r1 = min(r0 + POOLROWS, N);
    if (r0 >= N) return;
    float acc = 0.f;
    int cur = bidx[r0];
    for (int r = r0; r < r1; ++r) {
        int b = bidx[r];
        if (b != cur) {
            atomicAdd(&pooled[(size_t)cur * 192 + c], acc);
            acc = 0.f;
            cur = b;
        }
        acc += bf2f(f[(size_t)r * 192 + c]);
    }
    atomicAdd(&pooled[(size_t)cur * 192 + c], acc);
}

__global__ void mlp_kernel(const float* __restrict__ pooled,
                           const float* __restrict__ A1, const float* __restrict__ ba1,
                           const float* __restrict__ A2, const float* __restrict__ ba2,
                           float* __restrict__ out) {
    __shared__ float p[192];
    __shared__ float hid[256];
    const int b = blockIdx.x;
    const int t = threadIdx.x;
    if (t < 192) p[t] = pooled[(size_t)b * 192 + t];
    __syncthreads();
    float acc = ba1[t];
    for (int k = 0; k < 192; ++k) acc += p[k] * A1[(size_t)k * 256 + t];
    hid[t] = fmaxf(acc, 0.f);
    __syncthreads();
    if (t < 10) {
        float o = ba2[t];
        for (int k = 0; k < 256; ++k) o += hid[k] * A2[(size_t)k * 10 + t];
        out[(size_t)b * 10 + t] = o;
    }
}

extern "C" void kernel_launch(void* const* d_in, const int* in_sizes, int n_in,
                              void* d_out, int out_size, void* d_ws, size_t ws_size,
                              hipStream_t stream) {
    const float* x      = (const float*)d_in[0];
    const int*   map00  = (const int*)d_in[1];
    const int*   map01  = (const int*)d_in[2];
    const int*   map02  = (const int*)d_in[3];
    const int*   map10  = (const int*)d_in[4];
    const int*   map11  = (const int*)d_in[5];
    const int*   map12  = (const int*)d_in[6];
    const int*   bidx   = (const int*)d_in[7];
    const float* W00 = (const float*)d_in[9];  const float* b00 = (const float*)d_in[10];
    const float* W01 = (const float*)d_in[11]; const float* b01 = (const float*)d_in[12];
    const float* W02 = (const float*)d_in[13]; const float* b02 = (const float*)d_in[14];
    const float* W10 = (const float*)d_in[15]; const float* b10 = (const float*)d_in[16];
    const float* W11 = (const float*)d_in[17]; const float* b11 = (const float*)d_in[18];
    const float* W12 = (const float*)d_in[19]; const float* b12 = (const float*)d_in[20];
    const float* A1  = (const float*)d_in[21]; const float* ba1 = (const float*)d_in[22];
    const float* A2  = (const float*)d_in[23]; const float* ba2 = (const float*)d_in[24];

    const int N   = in_sizes[0] / 128;
    const int E   = in_sizes[1] / 2;
    const int NSB = (N + 511) >> SBSHIFT;      // 98 super-buckets of 512 nodes

    unsigned short* bufH = (unsigned short*)d_ws;                    // [N+1,192] bf16
    unsigned short* bufF = bufH + (size_t)(N + 1) * 192;             // [N,192] bf16
    float*    pooled = (float*)(bufF + (size_t)N * 192);             // [64,192] f32
    int*      cnt    = (int*)(pooled + 64 * 192);                    // 6*NSB
    unsigned* p1     = (unsigned*)(cnt + 6 * NSB);                   // 6*NSB*CAPSB
    unsigned* cols   = p1 + (size_t)6 * NSB * CAPSB;                 // 6*NSB*CAPCOL u32
    int*      rows   = (int*)(cols + (size_t)6 * NSB * CAPCOL + 16); // 6*N
    unsigned short* wpack = (unsigned short*)(rows + (size_t)6 * N); // 6*12288 bf16

    dim3 gemmGrid((N + 63) / 64, 3);
    dim3 p1Grid((E + CHUNK - 1) / CHUNK, 6);
    dim3 sortGrid(NSB, 6);
    dim3 aggGrid((N + 15) / 16, 3);            // 4 waves/block x 4 nodes/wave

    // build CSR for all 6 maps + pack weights + zero cnt/pooled/h-dummy
    prepack_w<<<7, 256, 0, stream>>>(W00, W01, W02, W10, W11, W12, wpack,
                                     bufH, N, cnt, NSB, pooled);
    part_coarse<<<p1Grid, PTHREADS, 0, stream>>>(map00, map01, map02,
                                                 map10, map11, map12,
                                                 E, NSB, cnt, p1);
    sb_sort<<<sortGrid, 1024, 0, stream>>>(NSB, N, cnt, p1, cols, rows);
    // layer 0
    gemm_mfma<0><<<gemmGrid, 256, 0, stream>>>(x, N, 128, wpack, b00, b01, b02, 0, bufH);
    csr_agg<<<aggGrid, 256, 0, stream>>>(bufH, rows, cols, N, NSB, 0, bufF);
    // layer 1
    gemm_mfma<1><<<gemmGrid, 256, 0, stream>>>(bufF, N, 192, wpack, b10, b11, b12, 3, bufH);
    csr_agg<<<aggGrid, 256, 0, stream>>>(bufH, rows, cols, N, NSB, 3, bufF);
    // pool + mlp
    pool_kernel<<<(N + POOLROWS - 1) / POOLROWS, 192, 0, stream>>>(bufF, bidx, N, pooled);
    mlp_kernel<<<64, 256, 0, stream>>>(pooled, A1, ba1, A2, ba2, (float*)d_out);
}

// Round 17
// 206.471 us; speedup vs baseline: 1.0892x; 1.0892x over previous
//
#include <hip/hip_runtime.h>
#include <hip/hip_bf16.h>

// ---------------------------------------------------------------------------
// DHN 2-layer hom-conv GNN.
// Round 17: quad-node csr_agg regressed (occupancy 64->38%) -> revert to r15
// dual-node (38.8us known). New lever: gemm computes all 3 g-columns per
// block (A staged once per K-step instead of 3x; acc[3][4]).
// ---------------------------------------------------------------------------

#define CAPSB 9216        // per-(map,SB) p1 capacity: mean 8192 + ~11 sigma
#define CAPCOL 12800      // cols capacity: CAPSB + 512*7 padding
#define CHUNK 4096        // edges per pass-1 block
#define PTHREADS 512
#define EPT 8             // CHUNK / PTHREADS
#define SBSHIFT 9         // 512 nodes per super-bucket
#define POOLROWS 32       // rows per pool block

typedef __attribute__((ext_vector_type(8))) short bf16x8;
typedef __attribute__((ext_vector_type(4))) float f32x4;

__device__ inline unsigned short f2bf(float x) {           // RNE f32 -> bf16
    union { float f; unsigned u; } c; c.f = x;
    unsigned r = (c.u + 0x7FFFu + ((c.u >> 16) & 1u)) >> 16;
    return (unsigned short)r;
}
__device__ inline float bf2f(unsigned u16) {
    union { unsigned u; float f; } c; c.u = (u16 & 0xffffu) << 16; return c.f;
}
__device__ inline float lo16f(unsigned v) {   // low bf16 of packed dword
    union { unsigned u; float f; } c; c.u = v << 16; return c.f;
}
__device__ inline float hi16f(unsigned v) {   // high bf16 of packed dword
    union { unsigned u; float f; } c; c.u = v & 0xffff0000u; return c.f;
}

// ---- pack 6 weight matrices -> [K/8][64][8] bf16 frags.
// block 6: zero h dummy row N + cnt (6*NSB) + pooled (64*192).
__global__ void prepack_w(const float* __restrict__ W0, const float* __restrict__ W1,
                          const float* __restrict__ W2, const float* __restrict__ W3,
                          const float* __restrict__ W4, const float* __restrict__ W5,
                          unsigned short* __restrict__ wp,
                          unsigned short* __restrict__ h, int N,
                          int* __restrict__ cnt, int NSB,
                          float* __restrict__ pooled) {
    const int m = blockIdx.x;
    if (m == 6) {
        for (int i = threadIdx.x; i < 192; i += 256) h[(size_t)N * 192 + i] = 0;
        for (int i = threadIdx.x; i < 6 * NSB; i += 256) cnt[i] = 0;
        for (int i = threadIdx.x; i < 64 * 192; i += 256) pooled[i] = 0.f;
        return;
    }
    const float* W = (m == 0) ? W0 : (m == 1) ? W1 : (m == 2) ? W2
                   : (m == 3) ? W3 : (m == 4) ? W4 : W5;
    const int K = (m < 3) ? 128 : 192;
    unsigned short* o = wp + (size_t)m * 12288;
    for (int idx = threadIdx.x; idx < K * 64; idx += 256) {
        int k = idx >> 6, col = idx & 63;
        o[((k >> 3) * 64 + col) * 8 + (k & 7)] = f2bf(W[idx]);
    }
}

// ---- bf16 MFMA gemm: h[:, 0:192] = in[M,K] @ [W0|W1|W2] + b, h bf16. ----
// One block = 64 rows x ALL 192 cols: A staged once per K-step (3x less A
// traffic), W staged per-K-step for 3 maps (12KB slice). 12 MFMA/wave/step.
template <int INBF16>
__global__ void gemm_mfma(const void* __restrict__ in_, int M, int K,
                          const unsigned short* __restrict__ wpack,
                          const float* __restrict__ b0, const float* __restrict__ b1,
                          const float* __restrict__ b2, int mslot,
                          unsigned short* __restrict__ h) {
    __shared__ __align__(16) unsigned short Ws[6144];   // 3 maps x 32k x 64 cols
    __shared__ __align__(16) unsigned short As[2048];   // 64 rows x 32 k, swizzled

    const int t = threadIdx.x;
    const int m0   = blockIdx.x * 64;
    const int lane = t & 63;
    const int wrow = (t >> 6) * 16;

    const int arow = t >> 2;
    const int aseg = t & 3;
    const int aswz = arow * 32 + ((aseg ^ ((arow >> 1) & 3)) << 3);
    const int grow = m0 + arow;

    const float*          ainf = (const float*)in_ + (size_t)grow * K + aseg * 8;
    const unsigned short* ainb = (const unsigned short*)in_ + (size_t)grow * K + aseg * 8;

    const int lrow = wrow + (lane & 15);
    const int aoff = lrow * 32 + ((((lane >> 4)) ^ ((lrow >> 1) & 3)) << 3);
    const int kq   = lane >> 4;

    const int* wsrc0 = (const int*)(wpack + (size_t)(mslot + 0) * 12288);
    const int* wsrc1 = (const int*)(wpack + (size_t)(mslot + 1) * 12288);
    const int* wsrc2 = (const int*)(wpack + (size_t)(mslot + 2) * 12288);

    f32x4 acc[3][4] = {};

    const int nsteps = K >> 5;
    for (int s = 0; s < nsteps; ++s) {
        __syncthreads();
        bf16x8 av = {};
        if (grow < M) {
            if (INBF16) {
                av = *reinterpret_cast<const bf16x8*>(ainb + s * 32);
            } else {
                float4 v0 = *reinterpret_cast<const float4*>(ainf + s * 32);
                float4 v1 = *reinterpret_cast<const float4*>(ainf + s * 32 + 4);
                av[0] = (short)f2bf(v0.x); av[1] = (short)f2bf(v0.y);
                av[2] = (short)f2bf(v0.z); av[3] = (short)f2bf(v0.w);
                av[4] = (short)f2bf(v1.x); av[5] = (short)f2bf(v1.y);
                av[6] = (short)f2bf(v1.z); av[7] = (short)f2bf(v1.w);
            }
        }
        *reinterpret_cast<bf16x8*>(&As[aswz]) = av;
        // stage W slice for this K-step: 3 maps x 1024 dwords
        {
            int i0 = s * 1024 + t;
            ((int*)Ws)[t]        = wsrc0[i0];
            ((int*)Ws)[t + 256]  = wsrc0[i0 + 256];
            ((int*)Ws)[t + 512]  = wsrc0[i0 + 512];
            ((int*)Ws)[t + 768]  = wsrc0[i0 + 768];
            ((int*)Ws)[t + 1024] = wsrc1[i0];
            ((int*)Ws)[t + 1280] = wsrc1[i0 + 256];
            ((int*)Ws)[t + 1536] = wsrc1[i0 + 512];
            ((int*)Ws)[t + 1792] = wsrc1[i0 + 768];
            ((int*)Ws)[t + 2048] = wsrc2[i0];
            ((int*)Ws)[t + 2304] = wsrc2[i0 + 256];
            ((int*)Ws)[t + 2560] = wsrc2[i0 + 512];
            ((int*)Ws)[t + 2816] = wsrc2[i0 + 768];
        }
        __syncthreads();

        bf16x8 af = *reinterpret_cast<const bf16x8*>(&As[aoff]);
        #pragma unroll
        for (int g = 0; g < 3; ++g) {
            #pragma unroll
            for (int n = 0; n < 4; ++n) {
                bf16x8 bfv = *reinterpret_cast<const bf16x8*>(
                    &Ws[(size_t)((g * 4 + kq) * 64 + n * 16 + (lane & 15)) * 8]);
                acc[g][n] = __builtin_amdgcn_mfma_f32_16x16x32_bf16(af, bfv, acc[g][n], 0, 0, 0);
            }
        }
    }

    #pragma unroll
    for (int g = 0; g < 3; ++g) {
        const float* bias = (g == 0) ? b0 : ((g == 1) ? b1 : b2);
        #pragma unroll
        for (int n = 0; n < 4; ++n) {
            int col = n * 16 + (lane & 15);
            float bv = bias[col];
            #pragma unroll
            for (int r = 0; r < 4; ++r) {
                int row = m0 + wrow + (lane >> 4) * 4 + r;
                if (row < M)
                    h[(size_t)row * 192 + g * 64 + col] = f2bf(acc[g][n][r] + bv);
            }
        }
    }
}

// ---- pass 1: coarse partition into 512-node super-buckets. ----
__global__ void part_coarse(const int* __restrict__ m0, const int* __restrict__ m1,
                            const int* __restrict__ m2, const int* __restrict__ m3,
                            const int* __restrict__ m4, const int* __restrict__ m5,
                            int E, int NSB, int* __restrict__ cnt,
                            unsigned* __restrict__ p1) {
    const int m = blockIdx.y;
    const int* mp = (m == 0) ? m0 : (m == 1) ? m1 : (m == 2) ? m2
                  : (m == 3) ? m3 : (m == 4) ? m4 : m5;
    __shared__ int hist[128];
    __shared__ int scanb[128];
    __shared__ int loff[128];
    __shared__ int delta[128];
    __shared__ unsigned stage[CHUNK];     // 16 KB
    const int c0 = blockIdx.x * CHUNK;
    const int t = threadIdx.x;

    int d[EPT]; unsigned srcs[EPT];
    #pragma unroll
    for (int k = 0; k < EPT; ++k) {
        int e = c0 + k * PTHREADS + t;
        bool v = e < E;
        d[k]    = v ? mp[e] : -1;
        srcs[k] = v ? (unsigned)mp[E + e] : 0u;
    }

    if (t < 128) hist[t] = 0;
    __syncthreads();
    #pragma unroll
    for (int k = 0; k < EPT; ++k)
        if (d[k] >= 0) atomicAdd(&hist[d[k] >> SBSHIFT], 1);
    __syncthreads();

    if (t < 128) scanb[t] = hist[t];
    __syncthreads();
    for (int off = 1; off < 128; off <<= 1) {
        int v = (t < 128 && t >= off) ? scanb[t - off] : 0;
        __syncthreads();
        if (t < 128) scanb[t] += v;
        __syncthreads();
    }
    if (t < NSB) {
        int c = hist[t];
        int lstart = scanb[t] - c;
        int gbase = (c > 0) ? atomicAdd(&cnt[m * NSB + t], c) : 0;
        loff[t]  = lstart;
        delta[t] = (m * NSB + t) * CAPSB + gbase - lstart;
    }
    __syncthreads();

    #pragma unroll
    for (int k = 0; k < EPT; ++k) {
        if (d[k] >= 0) {
            int sb = d[k] >> SBSHIFT;
            int pos = atomicAdd(&loff[sb], 1);
            stage[pos] = (srcs[k] << 16) | (unsigned)d[k];
        }
    }
    __syncthreads();

    const int total = scanb[127];
    for (int i = t; i < total; i += PTHREADS) {
        unsigned r = stage[i];
        int sb = (r & 0xffffu) >> SBSHIFT;
        int gidx = delta[sb] + i;
        if (gidx - (m * NSB + sb) * CAPSB < CAPSB)
            p1[gidx] = r;
    }
}

// ---- pass 2: per-(SB,map) counting sort -> padded CSR (u32 byte-offset cols).
__global__ void sb_sort(int NSB, int N, const int* __restrict__ cnt,
                        const unsigned* __restrict__ p1,
                        unsigned* __restrict__ cols, int* __restrict__ rows) {
    const int sb = blockIdx.x;
    const int m  = blockIdx.y;
    __shared__ unsigned rec[CAPSB];
    __shared__ int bin[512];
    __shared__ int pend[512];
    __shared__ int scanbuf[512];
    const int t = threadIdx.x;    // 0..1023
    const size_t basep = (size_t)(m * NSB + sb) * CAPSB;
    const size_t basec = (size_t)(m * NSB + sb) * CAPCOL;
    const int c = min(cnt[m * NSB + sb], CAPSB);

    for (int i = t; i < c; i += 1024) rec[i] = p1[basep + i];
    if (t < 512) bin[t] = 0;
    __syncthreads();
    for (int i = t; i < c; i += 1024)
        atomicAdd(&bin[rec[i] & 511], 1);
    __syncthreads();

    int p0 = 0;
    if (t < 512) { int b0 = bin[t]; p0 = (b0 + 7) & ~7; scanbuf[t] = p0; }
    __syncthreads();
    for (int off = 1; off < 512; off <<= 1) {
        int v = (t < 512 && t >= off) ? scanbuf[t - off] : 0;
        __syncthreads();
        if (t < 512) scanbuf[t] += v;
        __syncthreads();
    }
    if (t < 512) {
        int excl = scanbuf[t] - p0;
        bin[t]  = excl;
        pend[t] = excl + p0;
        int n = (sb << SBSHIFT) + t;
        if (n < N) rows[(size_t)m * N + n] = (int)(basec + pend[t]);
    }
    __syncthreads();

    for (int i = t; i < c; i += 1024) {
        unsigned r = rec[i];
        int pos = atomicAdd(&bin[r & 511], 1);
        cols[basec + pos] = (r >> 16) * 384u;    // byte offset of h row
    }
    __syncthreads();

    if (t < 512) {
        const unsigned dummy = (unsigned)N * 384u;
        for (int k = bin[t]; k < pend[t]; ++k)
            cols[basec + k] = dummy;
    }
}

// ---- two nodes per wave (r15 known-good); half-wave takes 4 edges of each ----
// ---- 8-edge group; cols are pre-scaled byte offsets.                     ----
__device__ inline void aggG(const char* __restrict__ hb,
                            const unsigned* __restrict__ cols,
                            int i, float& ax, float& ay) {  // one 8-edge group
    uint4 ca = *reinterpret_cast<const uint4*>(cols + i);   // i pre-offset by half
    unsigned v0 = *reinterpret_cast<const unsigned*>(hb + ca.x);
    unsigned v1 = *reinterpret_cast<const unsigned*>(hb + ca.y);
    unsigned v2 = *reinterpret_cast<const unsigned*>(hb + ca.z);
    unsigned v3 = *reinterpret_cast<const unsigned*>(hb + ca.w);
    ax += (lo16f(v0) + lo16f(v1)) + (lo16f(v2) + lo16f(v3));
    ay += (hi16f(v0) + hi16f(v1)) + (hi16f(v2) + hi16f(v3));
}

__global__ void csr_agg(const unsigned short* __restrict__ h, const int* __restrict__ rows,
                        const unsigned* __restrict__ cols, int N, int NSB, int mapBase,
                        unsigned short* __restrict__ f) {
    const int g = blockIdx.y;
    const int m = mapBase + g;
    const int lane = threadIdx.x & 63;
    const int half4 = (lane >> 5) << 2;  // 0: edges 0-3 of group, 4: edges 4-7
    const int fp = (lane & 31) * 2;      // feature pair base
    const int wid = (blockIdx.x * blockDim.x + threadIdx.x) >> 6;
    const int n0 = wid * 2;
    const int n1 = n0 + 1;
    if (n0 >= N) return;
    const bool has1 = (n1 < N);

    const size_t base0 = (size_t)(m * NSB + (n0 >> SBSHIFT)) * CAPCOL;
    int s0 = ((n0 & 511) == 0) ? (int)base0 : rows[(size_t)m * N + n0 - 1];
    int e0 = rows[(size_t)m * N + n0];
    int s1 = 0, e1 = 0;
    if (has1) {
        s1 = e0;                          // n1 odd -> never SB-start
        e1 = rows[(size_t)m * N + n1];
    }
    const char* hb = (const char*)(h + g * 64 + fp);

    float ax0 = 0.f, ay0 = 0.f, ax1 = 0.f, ay1 = 0.f;
    int i0 = s0 + half4, i1 = s1 + half4;
    const int f0 = e0 - 16 + half4, f1 = e1 - 16 + half4;  // last full-16 start

    while (i0 <= f0 && i1 <= f1) {
        uint4 ca = *reinterpret_cast<const uint4*>(cols + i0);
        uint4 cb = *reinterpret_cast<const uint4*>(cols + i0 + 8);
        uint4 cc = *reinterpret_cast<const uint4*>(cols + i1);
        uint4 cd = *reinterpret_cast<const uint4*>(cols + i1 + 8);
        unsigned va0 = *reinterpret_cast<const unsigned*>(hb + ca.x);
        unsigned va1 = *reinterpret_cast<const unsigned*>(hb + ca.y);
        unsigned va2 = *reinterpret_cast<const unsigned*>(hb + ca.z);
        unsigned va3 = *reinterpret_cast<const unsigned*>(hb + ca.w);
        unsigned vb0 = *reinterpret_cast<const unsigned*>(hb + cb.x);
        unsigned vb1 = *reinterpret_cast<const unsigned*>(hb + cb.y);
        unsigned vb2 = *reinterpret_cast<const unsigned*>(hb + cb.z);
        unsigned vb3 = *reinterpret_cast<const unsigned*>(hb + cb.w);
        unsigned vc0 = *reinterpret_cast<const unsigned*>(hb + cc.x);
        unsigned vc1 = *reinterpret_cast<const unsigned*>(hb + cc.y);
        unsigned vc2 = *reinterpret_cast<const unsigned*>(hb + cc.z);
        unsigned vc3 = *reinterpret_cast<const unsigned*>(hb + cc.w);
        unsigned vd0 = *reinterpret_cast<const unsigned*>(hb + cd.x);
        unsigned vd1 = *reinterpret_cast<const unsigned*>(hb + cd.y);
        unsigned vd2 = *reinterpret_cast<const unsigned*>(hb + cd.z);
        unsigned vd3 = *reinterpret_cast<const unsigned*>(hb + cd.w);
        ax0 += ((lo16f(va0) + lo16f(va1)) + (lo16f(va2) + lo16f(va3)))
             + ((lo16f(vb0) + lo16f(vb1)) + (lo16f(vb2) + lo16f(vb3)));
        ay0 += ((hi16f(va0) + hi16f(va1)) + (hi16f(va2) + hi16f(va3)))
             + ((hi16f(vb0) + hi16f(vb1)) + (hi16f(vb2) + hi16f(vb3)));
        ax1 += ((lo16f(vc0) + lo16f(vc1)) + (lo16f(vc2) + lo16f(vc3)))
             + ((lo16f(vd0) + lo16f(vd1)) + (lo16f(vd2) + lo16f(vd3)));
        ay1 += ((hi16f(vc0) + hi16f(vc1)) + (hi16f(vc2) + hi16f(vc3)))
             + ((hi16f(vd0) + hi16f(vd1)) + (hi16f(vd2) + hi16f(vd3)));
        i0 += 16; i1 += 16;
    }
    while (i0 <= f0) { aggG(hb, cols, i0, ax0, ay0); aggG(hb, cols, i0 + 8, ax0, ay0); i0 += 16; }
    while (i1 <= f1) { aggG(hb, cols, i1, ax1, ay1); aggG(hb, cols, i1 + 8, ax1, ay1); i1 += 16; }
    if (i0 < e0) aggG(hb, cols, i0, ax0, ay0);   // exactly 8 remain (x8-padded)
    if (i1 < e1) aggG(hb, cols, i1, ax1, ay1);

    ax0 += __shfl_xor(ax0, 32); ay0 += __shfl_xor(ay0, 32);
    ax1 += __shfl_xor(ax1, 32); ay1 += __shfl_xor(ay1, 32);
    if (half4 == 0) {
        unsigned pk0 = (unsigned)f2bf(fmaxf(ax0, 0.f)) | ((unsigned)f2bf(fmaxf(ay0, 0.f)) << 16);
        *reinterpret_cast<unsigned*>(f + (size_t)n0 * 192 + g * 64 + fp) = pk0;
        if (has1) {
            unsigned pk1 = (unsigned)f2bf(fmaxf(ax1, 0.f)) | ((unsigned)f2bf(fmaxf(ay1, 0.f)) << 16);
            *reinterpret_cast<unsigned*>(f + (size_t)n1 * 192 + g * 64 + fp) = pk1;
        }
    }
}

// segment-pool bf16 f by sorted batch_idx; 32-row chunks for occupancy.
__global__ void pool_kernel(const unsigned short* __restrict__ f, const int* __restrict__ bidx,
                            int N, float* __restrict__ pooled) {
    const int c  = threadIdx.x;          // 0..191
    const int r0 = blockIdx.x * POOLROWS;
    const int r1 = min(r0 + POOLROWS, N);
    if (r0 >= N) return;
    float acc = 0.f;
    int cur = bidx[r0];
    for (int r = r0; r < r1; ++r) {
        int b = bidx[r];
        if (b != cur) {
            atomicAdd(&pooled[(size_t)cur * 192 + c], acc);
            acc = 0.f;
            cur = b;
        }
        acc += bf2f(f[(size_t)r * 192 + c]);
    }
    atomicAdd(&pooled[(size_t)cur * 192 + c], acc);
}

__global__ void mlp_kernel(const float* __restrict__ pooled,
                           const float* __restrict__ A1, const float* __restrict__ ba1,
                           const float* __restrict__ A2, const float* __restrict__ ba2,
                           float* __restrict__ out) {
    __shared__ float p[192];
    __shared__ float hid[256];
    const int b = blockIdx.x;
    const int t = threadIdx.x;
    if (t < 192) p[t] = pooled[(size_t)b * 192 + t];
    __syncthreads();
    float acc = ba1[t];
    for (int k = 0; k < 192; ++k) acc += p[k] * A1[(size_t)k * 256 + t];
    hid[t] = fmaxf(acc, 0.f);
    __syncthreads();
    if (t < 10) {
        float o = ba2[t];
        for (int k = 0; k < 256; ++k) o += hid[k] * A2[(size_t)k * 10 + t];
        out[(size_t)b * 10 + t] = o;
    }
}

extern "C" void kernel_launch(void* const* d_in, const int* in_sizes, int n_in,
                              void* d_out, int out_size, void* d_ws, size_t ws_size,
                              hipStream_t stream) {
    const float* x      = (const float*)d_in[0];
    const int*   map00  = (const int*)d_in[1];
    const int*   map01  = (const int*)d_in[2];
    const int*   map02  = (const int*)d_in[3];
    const int*   map10  = (const int*)d_in[4];
    const int*   map11  = (const int*)d_in[5];
    const int*   map12  = (const int*)d_in[6];
    const int*   bidx   = (const int*)d_in[7];
    const float* W00 = (const float*)d_in[9];  const float* b00 = (const float*)d_in[10];
    const float* W01 = (const float*)d_in[11]; const float* b01 = (const float*)d_in[12];
    const float* W02 = (const float*)d_in[13]; const float* b02 = (const float*)d_in[14];
    const float* W10 = (const float*)d_in[15]; const float* b10 = (const float*)d_in[16];
    const float* W11 = (const float*)d_in[17]; const float* b11 = (const float*)d_in[18];
    const float* W12 = (const float*)d_in[19]; const float* b12 = (const float*)d_in[20];
    const float* A1  = (const float*)d_in[21]; const float* ba1 = (const float*)d_in[22];
    const float* A2  = (const float*)d_in[23]; const float* ba2 = (const float*)d_in[24];

    const int N   = in_sizes[0] / 128;
    const int E   = in_sizes[1] / 2;
    const int NSB = (N + 511) >> SBSHIFT;      // 98 super-buckets of 512 nodes

    unsigned short* bufH = (unsigned short*)d_ws;                    // [N+1,192] bf16
    unsigned short* bufF = bufH + (size_t)(N + 1) * 192;             // [N,192] bf16
    float*    pooled = (float*)(bufF + (size_t)N * 192);             // [64,192] f32
    int*      cnt    = (int*)(pooled + 64 * 192);                    // 6*NSB
    unsigned* p1     = (unsigned*)(cnt + 6 * NSB);                   // 6*NSB*CAPSB
    unsigned* cols   = p1 + (size_t)6 * NSB * CAPSB;                 // 6*NSB*CAPCOL u32
    int*      rows   = (int*)(cols + (size_t)6 * NSB * CAPCOL + 16); // 6*N
    unsigned short* wpack = (unsigned short*)(rows + (size_t)6 * N); // 6*12288 bf16

    dim3 gemmGrid((N + 63) / 64);
    dim3 p1Grid((E + CHUNK - 1) / CHUNK, 6);
    dim3 sortGrid(NSB, 6);
    dim3 aggGrid((N + 7) / 8, 3);              // 4 waves/block x 2 nodes/wave

    // build CSR for all 6 maps + pack weights + zero cnt/pooled/h-dummy
    prepack_w<<<7, 256, 0, stream>>>(W00, W01, W02, W10, W11, W12, wpack,
                                     bufH, N, cnt, NSB, pooled);
    part_coarse<<<p1Grid, PTHREADS, 0, stream>>>(map00, map01, map02,
                                                 map10, map11, map12,
                                                 E, NSB, cnt, p1);
    sb_sort<<<sortGrid, 1024, 0, stream>>>(NSB, N, cnt, p1, cols, rows);
    // layer 0
    gemm_mfma<0><<<gemmGrid, 256, 0, stream>>>(x, N, 128, wpack, b00, b01, b02, 0, bufH);
    csr_agg<<<aggGrid, 256, 0, stream>>>(bufH, rows, cols, N, NSB, 0, bufF);
    // layer 1
    gemm_mfma<1><<<gemmGrid, 256, 0, stream>>>(bufF, N, 192, wpack, b10, b11, b12, 3, bufH);
    csr_agg<<<aggGrid, 256, 0, stream>>>(bufH, rows, cols, N, NSB, 3, bufF);
    // pool + mlp
    pool_kernel<<<(N + POOLROWS - 1) / POOLROWS, 192, 0, stream>>>(bufF, bidx, N, pooled);
    mlp_kernel<<<64, 256, 0, stream>>>(pooled, A1, ba1, A2, ba2, (float*)d_out);
}